// Round 5
// baseline (182.892 us; speedup 1.0000x reference)
//
#include <hip/hip_runtime.h>
#include <hip/hip_bf16.h>
#include <stdint.h>

typedef __attribute__((ext_vector_type(8))) short bfrag;
typedef __attribute__((ext_vector_type(4))) short bfrag4;
typedef __attribute__((ext_vector_type(4))) float f32x4;
typedef __attribute__((ext_vector_type(2))) float f32x2;
typedef __attribute__((ext_vector_type(2))) unsigned int u32x2;

__device__ inline short f2bf(float f) {
  union { float f; uint32_t u; } v; v.f = f;
  uint32_t u = v.u;
  uint32_t r = (u + 0x7fffu + ((u >> 16) & 1u)) >> 16;
  return (short)r;
}

#if __has_builtin(__builtin_amdgcn_cvt_pk_bf16_f32)
typedef __attribute__((ext_vector_type(2))) __bf16 bf16x2_t;
__device__ inline uint32_t pack_bf16(float a, float b) {
  bf16x2_t r = __builtin_amdgcn_cvt_pk_bf16_f32(a, b);
  return __builtin_bit_cast(uint32_t, r);
}
#else
// pack two floats to bf16 pair (a -> low half, b -> high half), round-half-away
__device__ inline uint32_t pack_bf16(float a, float b) {
  uint32_t ua = __builtin_bit_cast(uint32_t, a) + 0x8000u;
  uint32_t ub = __builtin_bit_cast(uint32_t, b) + 0x8000u;
  return __builtin_amdgcn_perm(ub, ua, 0x07060302);
}
#endif

// ---------------- ada: sc/sh = silu(emb_table[t]) @ ada_w + ada_b ----------
__global__ __launch_bounds__(256) void ada_kernel(
    const float* __restrict__ emb_table, const int* __restrict__ t,
    const float* __restrict__ ada_w, const float* __restrict__ ada_b,
    float* __restrict__ scsh) {
  int b = blockIdx.y;
  int tid = threadIdx.x;
  __shared__ float se[256];
  __shared__ float part[256];
  int tt = t[b];
  float e = emb_table[tt * 256 + tid];
  se[tid] = e / (1.f + __expf(-e));
  __syncthreads();
  int ol = tid & 63, kc = tid >> 6;
  int o = blockIdx.x * 64 + ol;
  float acc = 0.f;
#pragma unroll 8
  for (int k = kc * 64; k < (kc + 1) * 64; ++k) acc += se[k] * ada_w[k * 512 + o];
  part[tid] = acc;
  __syncthreads();
  if (tid < 64) {
    int oo = blockIdx.x * 64 + tid;
    scsh[b * 512 + oo] =
        part[tid] + part[64 + tid] + part[128 + tid] + part[192 + tid] + ada_b[oo];
  }
}

// ---------------- weight transpose + fp32->bf16: Wt[n][k] = W[k][n], K=256 --
__global__ __launch_bounds__(256) void transpose_w(const float* __restrict__ W,
                                                   short* __restrict__ Wt, int N) {
  __shared__ float tile[64][65];
  int k0 = blockIdx.x * 64, n0 = blockIdx.y * 64;
  int tid = threadIdx.x;
  int r = tid >> 2, c0 = (tid & 3) * 16;
  const float* src = W + (long)(k0 + r) * N + n0 + c0;
#pragma unroll
  for (int j = 0; j < 16; j += 4) {
    float4 v = *(const float4*)(src + j);
    tile[r][c0 + j] = v.x; tile[r][c0 + j + 1] = v.y;
    tile[r][c0 + j + 2] = v.z; tile[r][c0 + j + 3] = v.w;
  }
  __syncthreads();
  int nl = tid >> 2, kc = (tid & 3) * 16;
  short outv[16];
#pragma unroll
  for (int j = 0; j < 16; ++j) outv[j] = f2bf(tile[kc + j][nl]);
  short* dst = Wt + (long)(n0 + nl) * 256 + k0 + kc;
  *(bfrag*)dst = *(bfrag*)&outv[0];
  *(bfrag*)(dst + 8) = *(bfrag*)&outv[8];
}

// ---------------- LayerNorm + (1+sc)*xn + sh -> bf16 ----------------------
__global__ __launch_bounds__(256) void ln_kernel(const float* __restrict__ x,
                                                 const float* __restrict__ scsh,
                                                 short* __restrict__ xb) {
  int row = blockIdx.x;            // 0..8191
  int b = row >> 12;
  int i = threadIdx.x;
  float v = x[(long)row * 256 + i];
  float s = v, sq = v * v;
#pragma unroll
  for (int off = 32; off > 0; off >>= 1) {
    s += __shfl_down(s, off);
    sq += __shfl_down(sq, off);
  }
  __shared__ float red[8];
  int w = i >> 6;
  if ((i & 63) == 0) { red[w] = s; red[4 + w] = sq; }
  __syncthreads();
  s = red[0] + red[1] + red[2] + red[3];
  sq = red[4] + red[5] + red[6] + red[7];
  float mu = s * (1.f / 256.f);
  float var = sq * (1.f / 256.f) - mu * mu;
  float xn = (v - mu) * rsqrtf(var + 1e-5f);
  float y = xn * (1.f + scsh[b * 512 + i]) + scsh[b * 512 + 256 + i];
  xb[(long)row * 256 + i] = f2bf(y);
}

// ---------------- bf16 MFMA GEMM over A[M,256] * Bt[N,256]^T + bias --------
// mode 0 (QKV): cols 0..511 -> qk[row*512+col] bf16 (cols<256 scaled by qscale);
//               cols 512..767 -> vT[(b*8+h)*32 + d&31][key] bf16 (transposed).
// mode 1 (proj): fp32, pitch N, into cout.
__global__ __launch_bounds__(256) void gemm_bf16(const short* __restrict__ A,
                                                 const short* __restrict__ Bt,
                                                 const float* __restrict__ bias,
                                                 int N, int mode, float qscale,
                                                 short* __restrict__ qk,
                                                 short* __restrict__ vT,
                                                 float* __restrict__ cout) {
  __shared__ short As[64 * 40];
  __shared__ short Bs[64 * 40];
  const int mt = blockIdx.x, nt = blockIdx.y;
  const int tid = threadIdx.x;
  const int w = tid >> 6, lane = tid & 63, l16 = lane & 15, quad = lane >> 4;
  const int si = tid >> 2, sk = (tid & 3) * 8;
  f32x4 acc[4] = {{0,0,0,0},{0,0,0,0},{0,0,0,0},{0,0,0,0}};
  const short* Arow = A + (long)(mt * 64 + si) * 256 + sk;
  const short* Brow = Bt + (long)(nt * 64 + si) * 256 + sk;
  for (int kk = 0; kk < 8; ++kk) {
    __syncthreads();
    *(bfrag*)&As[si * 40 + sk] = *(const bfrag*)(Arow + kk * 32);
    *(bfrag*)&Bs[si * 40 + sk] = *(const bfrag*)(Brow + kk * 32);
    __syncthreads();
    bfrag a = *(const bfrag*)&As[(w * 16 + l16) * 40 + quad * 8];
#pragma unroll
    for (int c = 0; c < 4; ++c) {
      bfrag bf = *(const bfrag*)&Bs[(c * 16 + l16) * 40 + quad * 8];
      acc[c] = __builtin_amdgcn_mfma_f32_16x16x32_bf16(a, bf, acc[c], 0, 0, 0);
    }
  }
  const int row0 = mt * 64 + w * 16 + quad * 4;
  if (mode == 1) {
#pragma unroll
    for (int c = 0; c < 4; ++c) {
      int col = nt * 64 + c * 16 + l16;
      float bv = bias[col];
#pragma unroll
      for (int r = 0; r < 4; ++r)
        cout[(long)(row0 + r) * N + col] = acc[c][r] + bv;
    }
  } else if (nt < 8) {  // Q,K columns -> qk pitch 512
#pragma unroll
    for (int c = 0; c < 4; ++c) {
      int col = nt * 64 + c * 16 + l16;
      float bv = bias[col];
      float mult = (col < 256) ? qscale : 1.0f;
#pragma unroll
      for (int r = 0; r < 4; ++r)
        qk[(long)(row0 + r) * 512 + col] = f2bf((acc[c][r] + bv) * mult);
    }
  } else {  // V columns -> vT[bh][d][key], key-contiguous dwordx2 stores
    const int bb = mt >> 6;          // batch of this row-tile (uniform)
    const int keyl = row0 & 4095;
#pragma unroll
    for (int c = 0; c < 4; ++c) {
      int col = nt * 64 + c * 16 + l16;
      float bv = bias[col];
      int d = col - 512;             // 0..255
      u32x2 dd;
      dd.x = pack_bf16(acc[c][0] + bv, acc[c][1] + bv);
      dd.y = pack_bf16(acc[c][2] + bv, acc[c][3] + bv);
      *(u32x2*)&vT[((long)(bb * 8 + (d >> 5)) * 32 + (d & 31)) * 4096 + keyl] = dd;
    }
  }
}

// ---------------- flash attention (S^T scheme, 2-way key split) ------------
// Grid: qt(32) x bh(16) x ks(2). Each block: 128 q rows, keys [ks*2048, +2048).
// No max-tracking => partials combine linearly: block writes unnormalized
// O-numerator (f32) and denominator l to scratch; reduce_kernel combines.
__global__ __launch_bounds__(256) void attn_kernel(const short* __restrict__ qk,
                                                   const short* __restrict__ vT,
                                                   float* __restrict__ Opart,
                                                   float* __restrict__ lpart) {
  const int blk = blockIdx.x;
  const int qt = blk & 31;          // q tile (128 rows)
  const int bh = (blk >> 5) & 15;   // 0..15
  const int ks = blk >> 9;          // key split 0/1
  const int b = bh >> 3, hh = bh & 7;
  const int tid = threadIdx.x;
  const int w = tid >> 6, lane = tid & 63, l16 = lane & 15, quad = lane >> 4;

  __shared__ short Ks[2][64 * 40];   // K tile, row=key(64), pitch 40
  __shared__ short Vt[2][32 * 68];   // V^T tile, row=d(32), col=key(64), pitch 68

  const long rowbase = (long)b * 4096;
  // Q fragments (B-operand): n=l16 -> q row, k=quad*8+j -> d
  const int qrow0 = qt * 128 + w * 32 + l16;
  bfrag qf0 = *(const bfrag*)&qk[(rowbase + qrow0) * 512 + hh * 32 + quad * 8];
  bfrag qf1 = *(const bfrag*)&qk[(rowbase + qrow0 + 16) * 512 + hh * 32 + quad * 8];

  f32x4 o00 = {0,0,0,0}, o10 = {0,0,0,0};  // q-group 0: d 0-15, 16-31
  f32x4 o01 = {0,0,0,0}, o11 = {0,0,0,0};  // q-group 1
  f32x2 l0 = {0.f, 0.f}, l1 = {0.f, 0.f};  // per-lane partial denominators

  // staging addresses
  const int si = tid >> 2, sk = (tid & 3) * 8;          // K: 64 rows x 32 d
  const int vrow = tid >> 3, vcol = (tid & 7) * 8;      // V^T: 32 rows x 64 keys
  const short* ksrc = qk + rowbase * 512 + 256 + hh * 32 + (long)si * 512 + sk;
  const short* vsrc = vT + ((long)bh * 32 + vrow) * 4096 + vcol;

  const int kt0 = ks * 32;
  bfrag k8 = *(const bfrag*)(ksrc + (long)kt0 * 64 * 512);
  bfrag v8 = *(const bfrag*)(vsrc + kt0 * 64);

  int buf = 0;
  for (int i = 0; i < 32; ++i) {
    *(bfrag*)&Ks[buf][si * 40 + sk] = k8;
    *(bfrag*)&Vt[buf][vrow * 68 + vcol] = v8;
    // prefetch next tile (clamped on last iter; value unused)
    int nn = (i < 31) ? (i + 1) : 31;
    k8 = *(const bfrag*)(ksrc + (long)(kt0 + nn) * 64 * 512);
    v8 = *(const bfrag*)(vsrc + (kt0 + nn) * 64);
    __syncthreads();

    // S^T = K Q^T
    f32x4 s0[4], s1[4];
#pragma unroll
    for (int nt = 0; nt < 4; ++nt) {
      bfrag kf = *(const bfrag*)&Ks[buf][(nt * 16 + l16) * 40 + quad * 8];
      f32x4 z = {0,0,0,0};
      s0[nt] = __builtin_amdgcn_mfma_f32_16x16x32_bf16(kf, qf0, z, 0, 0, 0);
      s1[nt] = __builtin_amdgcn_mfma_f32_16x16x32_bf16(kf, qf1, z, 0, 0, 0);
    }
    // p = exp2(s); accumulate per-lane partial sums; pack to bf16 B-frags
    bfrag4 pb0[4], pb1[4];
#pragma unroll
    for (int nt = 0; nt < 4; ++nt) {
      float a0 = __builtin_amdgcn_exp2f(s0[nt][0]);
      float a1 = __builtin_amdgcn_exp2f(s0[nt][1]);
      float a2 = __builtin_amdgcn_exp2f(s0[nt][2]);
      float a3 = __builtin_amdgcn_exp2f(s0[nt][3]);
      f32x2 pa = {a0, a1}, pc = {a2, a3};
      l0 += pa; l0 += pc;
      u32x2 pk0; pk0.x = pack_bf16(a0, a1); pk0.y = pack_bf16(a2, a3);
      pb0[nt] = __builtin_bit_cast(bfrag4, pk0);
      float b0 = __builtin_amdgcn_exp2f(s1[nt][0]);
      float b1 = __builtin_amdgcn_exp2f(s1[nt][1]);
      float b2 = __builtin_amdgcn_exp2f(s1[nt][2]);
      float b3 = __builtin_amdgcn_exp2f(s1[nt][3]);
      f32x2 pb = {b0, b1}, pd = {b2, b3};
      l1 += pb; l1 += pd;
      u32x2 pk1; pk1.x = pack_bf16(b0, b1); pk1.y = pack_bf16(b2, b3);
      pb1[nt] = __builtin_bit_cast(bfrag4, pk1);
    }
    // O^T += V^T P^T (each V fragment feeds both q-groups)
#pragma unroll
    for (int nt = 0; nt < 4; ++nt) {
      bfrag4 va = *(const bfrag4*)&Vt[buf][l16 * 68 + nt * 16 + quad * 4];
      bfrag4 vb = *(const bfrag4*)&Vt[buf][(16 + l16) * 68 + nt * 16 + quad * 4];
      o00 = __builtin_amdgcn_mfma_f32_16x16x16bf16_1k(va, pb0[nt], o00, 0, 0, 0);
      o10 = __builtin_amdgcn_mfma_f32_16x16x16bf16_1k(vb, pb0[nt], o10, 0, 0, 0);
      o01 = __builtin_amdgcn_mfma_f32_16x16x16bf16_1k(va, pb1[nt], o01, 0, 0, 0);
      o11 = __builtin_amdgcn_mfma_f32_16x16x16bf16_1k(vb, pb1[nt], o11, 0, 0, 0);
    }
    buf ^= 1;
  }
  // block-level denominator: lanes {l16,+16,+32,+48} hold disjoint keys
  float ls0 = l0.x + l0.y, ls1 = l1.x + l1.y;
  ls0 += __shfl_xor(ls0, 16); ls0 += __shfl_xor(ls0, 32);
  ls1 += __shfl_xor(ls1, 16); ls1 += __shfl_xor(ls1, 32);
  // write unnormalized numerators + denominators
  const long pbase0 = (((long)ks * 16 + bh) * 4096 + qrow0) * 32;
  const long pbase1 = pbase0 + 16 * 32;
  *(f32x4*)&Opart[pbase0 + quad * 4] = o00;
  *(f32x4*)&Opart[pbase0 + 16 + quad * 4] = o10;
  *(f32x4*)&Opart[pbase1 + quad * 4] = o01;
  *(f32x4*)&Opart[pbase1 + 16 + quad * 4] = o11;
  if (quad == 0) {
    lpart[((long)ks * 16 + bh) * 4096 + qrow0] = ls0;
    lpart[((long)ks * 16 + bh) * 4096 + qrow0 + 16] = ls1;
  }
}

// ---------------- combine key-split partials -> attn_out bf16 --------------
__global__ __launch_bounds__(256) void reduce_kernel(const float* __restrict__ Opart,
                                                     const float* __restrict__ lpart,
                                                     short* __restrict__ attn_out) {
  int row = blockIdx.x;            // 0..8191 = b*4096 + q
  int bq = row >> 12, q = row & 4095;
  int d = threadIdx.x;             // 0..255
  int h2 = d >> 5, dd = d & 31;
  int bh = bq * 8 + h2;
  long i0 = (((long)bh) * 4096 + q) * 32 + dd;
  long i1 = i0 + (long)16 * 4096 * 32;
  float l0 = lpart[(long)bh * 4096 + q];
  float l1 = lpart[(long)(16 + bh) * 4096 + q];
  float val = (Opart[i0] + Opart[i1]) / (l0 + l1);
  attn_out[(long)row * 256 + d] = f2bf(val);
}

extern "C" void kernel_launch(void* const* d_in, const int* in_sizes, int n_in,
                              void* d_out, int out_size, void* d_ws, size_t ws_size,
                              hipStream_t stream) {
  const float* x      = (const float*)d_in[0];
  // d_in[1] = cond (unused by reference)
  const int*   t      = (const int*)d_in[2];
  const float* emb    = (const float*)d_in[3];
  const float* ada_w  = (const float*)d_in[4];
  const float* ada_b  = (const float*)d_in[5];
  const float* qkv_w  = (const float*)d_in[6];
  const float* qkv_b  = (const float*)d_in[7];
  const float* proj_w = (const float*)d_in[8];
  const float* proj_b = (const float*)d_in[9];

  char* ws = (char*)d_ws;
  float* scsh     = (float*)(ws);                  //   4 KB  [2][512]
  short* qkv_wt   = (short*)(ws + 4096);           // 384 KB  [768][256]
  short* proj_wt  = (short*)(ws + 397312);         // 128 KB  [256][256]
  short* xb       = (short*)(ws + 528384);         //   4 MB  [8192][256]
  short* qk_out   = (short*)(ws + 4722688);        //   8 MB  [8192][512]
  short* vT       = (short*)(ws + 13111296);       //   4 MB  [16][32][4096]
  short* attn_out = (short*)(ws + 17305600);       //   4 MB  [8192][256]
  float* Opart    = (float*)(ws + 21499904);       //  16 MB  [2][16][4096][32]
  float* lpart    = (float*)(ws + 38277120);       // 512 KB  [2][16][4096]

  // scale * log2(e): softmax done in exp2 domain, folded into Q columns
  const float QS = 0.17677669529663687f * 1.4426950408889634f;

  ada_kernel<<<dim3(8, 2), 256, 0, stream>>>(emb, t, ada_w, ada_b, scsh);
  transpose_w<<<dim3(4, 12), 256, 0, stream>>>(qkv_w, qkv_wt, 768);
  transpose_w<<<dim3(4, 4), 256, 0, stream>>>(proj_w, proj_wt, 256);
  ln_kernel<<<8192, 256, 0, stream>>>(x, scsh, xb);
  gemm_bf16<<<dim3(128, 12), 256, 0, stream>>>(xb, qkv_wt, qkv_b, 768, 0, QS,
                                               qk_out, vT, nullptr);
  attn_kernel<<<1024, 256, 0, stream>>>(qk_out, vT, Opart, lpart);
  reduce_kernel<<<8192, 256, 0, stream>>>(Opart, lpart, attn_out);
  gemm_bf16<<<dim3(128, 4), 256, 0, stream>>>(attn_out, proj_wt, proj_b, 256, 1,
                                              1.0f, nullptr, nullptr, (float*)d_out);
}